// Round 9
// baseline (421.113 us; speedup 1.0000x reference)
//
#include <hip/hip_runtime.h>
#include <cstdint>
#include <cstddef>

#define N_NODES 8192
#define IN_DIM  256
#define OUT_DIM 64
#define HEADS   2
#define FEAT    128           // OUT_DIM*HEADS
#define NTILES  9             // 144 B-cols: 128 feat + 2 denom + 14 pad
#define ACC_STRIDE 132
#define KSPLIT  8
#define PREP_BLOCKS 256       // blocks 0..255 prep; 256..2303 pack

typedef __bf16 bf16x8 __attribute__((ext_vector_type(8)));
typedef float  f32x4  __attribute__((ext_vector_type(4)));
typedef int    i32x4  __attribute__((ext_vector_type(4)));
typedef unsigned uu32x4 __attribute__((ext_vector_type(4)));

static __device__ __forceinline__ unsigned short f2bf(float f) {
  unsigned u = __float_as_uint(f);
  u += 0x7FFFu + ((u >> 16) & 1u);     // round-to-nearest-even
  return (unsigned short)(u >> 16);
}

// ---------------------------------------------------------------- k_prep_pack
// Heterogeneous fused launch (independent jobs, co-resident):
//  blocks 0..255:    H-tile matmul + er reduction + exp + bf16 frag pack
//                    (identical to round-8 k_prep).
//  blocks 256..2303: streaming bit-pack 268 MB adj -> 8 MB bitmask
//                    (identical to round-8 k_pack; COALESCED: wave reads 1 KB
//                    contiguous per instruction — round 5's failure was the
//                    64-lines-per-instruction strided variant, 4x line
//                    amplification, not occupancy).
// Pack occupancy under prep's 53 KB LDS / 184 VGPR: ~12 waves/CU x 8 KB
// in flight = 96 KB/CU >> 9.2 KB BW-latency product -> still HBM-bound.
__global__ __launch_bounds__(256) void k_prep_pack(const float* __restrict__ x,
                                                   const float* __restrict__ W,
                                                   const float* __restrict__ attn_r,
                                                   const int* __restrict__ adj,
                                                   uint4* __restrict__ frag,
                                                   unsigned long long* __restrict__ bm64) {
  __shared__ float xs[32][68];               // [row][k] 8.7 KB
  __shared__ float wl[128][68];              // [col][k] 34.8 KB
  __shared__ unsigned short pk[32][146];     // bf16 pack buffer 9.3 KB

  const int tid = threadIdx.x;

  if (blockIdx.x >= PREP_BLOCKS) {
    // ---- pack path ----
    const int wv = tid >> 6, lane = tid & 63;
    const int row = (blockIdx.x - PREP_BLOCKS) * 4 + wv;
    const i32x4* rp = (const i32x4*)(adj + (size_t)row * N_NODES) + lane;
    unsigned long long* op = bm64 + (size_t)row * 128;

    for (int c = 0; c < 32; c += 8) {
      i32x4 v[8];
#pragma unroll
      for (int i = 0; i < 8; ++i)
        v[i] = __builtin_nontemporal_load(rp + (size_t)(c + i) * 64);
#pragma unroll
      for (int i = 0; i < 8; ++i) {
        unsigned long long m0 = __ballot(v[i][0] != 0);
        unsigned long long m1 = __ballot(v[i][1] != 0);
        unsigned long long m2 = __ballot(v[i][2] != 0);
        unsigned long long m3 = __ballot(v[i][3] != 0);
        unsigned long long mv = (lane == 0) ? m0 : (lane == 1) ? m1
                              : (lane == 2) ? m2 : m3;
        if (lane < 4) op[(c + i) * 4 + lane] = mv;
      }
    }
    return;
  }

  // ---- prep path ----
  const int kb = blockIdx.x;                 // 0..255
  const int tx = tid & 15, ty = tid >> 4;    // ty 0..15
  const int j0 = kb * 32;

  float acc[2][8] = {};                      // rows ty, ty+16; cols tx+jj*16

  for (int kc = 0; kc < IN_DIM; kc += 64) {
    __syncthreads();
#pragma unroll
    for (int p = 0; p < 2; p++) {
      const int slot = p*256 + tid;
      const int r = slot >> 4, k4 = slot & 15;
      *(float4*)&xs[r][k4*4] = *(const float4*)(x + (size_t)(j0 + r)*IN_DIM + kc + k4*4);
    }
#pragma unroll
    for (int p = 0; p < 8; p++) {
      const int slot = p*256 + tid;
      const int r = slot >> 4, k4 = slot & 15;
      *(float4*)&wl[r][k4*4] = *(const float4*)(W + (size_t)r*IN_DIM + kc + k4*4);
    }
    __syncthreads();
#pragma unroll
    for (int k4 = 0; k4 < 16; k4++) {
      float4 xr[2], wr[8];
#pragma unroll
      for (int i = 0; i < 2; i++) xr[i] = *(const float4*)&xs[ty + i*16][k4*4];
#pragma unroll
      for (int jj = 0; jj < 8; jj++) wr[jj] = *(const float4*)&wl[tx + jj*16][k4*4];
#pragma unroll
      for (int i = 0; i < 2; i++)
#pragma unroll
        for (int jj = 0; jj < 8; jj++)
          acc[i][jj] += xr[i].x*wr[jj].x + xr[i].y*wr[jj].y +
                        xr[i].z*wr[jj].z + xr[i].w*wr[jj].w;
    }
  }

  float ar[8];
#pragma unroll
  for (int jj = 0; jj < 8; jj++)
    ar[jj] = attn_r[((jj >> 2)) * OUT_DIM + ((tx + jj*16) & 63)];
  float e0[2] = {}, e1[2] = {};
#pragma unroll
  for (int i = 0; i < 2; i++) {
#pragma unroll
    for (int jj = 0; jj < 4; jj++) e0[i] += acc[i][jj] * ar[jj];
#pragma unroll
    for (int jj = 4; jj < 8; jj++) e1[i] += acc[i][jj] * ar[jj];
  }
#pragma unroll
  for (int m = 1; m <= 8; m <<= 1) {
#pragma unroll
    for (int i = 0; i < 2; i++) {
      e0[i] += __shfl_xor(e0[i], m);
      e1[i] += __shfl_xor(e1[i], m);
    }
  }
  float w0[2], w1[2];
#pragma unroll
  for (int i = 0; i < 2; i++) { w0[i] = __expf(e0[i]); w1[i] = __expf(e1[i]); }

#pragma unroll
  for (int i = 0; i < 2; i++) {
    const int row = ty + i*16;
#pragma unroll
    for (int jj = 0; jj < 8; jj++)
      pk[row][tx + jj*16] = f2bf((jj < 4 ? w0[i] : w1[i]) * acc[i][jj]);
    pk[row][128 + tx] = (tx == 0) ? f2bf(w0[i]) : (tx == 1) ? f2bf(w1[i]) : 0;
  }
  __syncthreads();

#pragma unroll
  for (int t = 0; t < 3; t++) {
    const int wid = t*256 + tid;
    if (wid < 576) {
      const int l = wid & 63, n = wid >> 6;
      const int col = n*16 + (l & 15), jb = (l >> 4) * 8;
      uint4 o;
      o.x = (unsigned)pk[jb+0][col] | ((unsigned)pk[jb+1][col] << 16);
      o.y = (unsigned)pk[jb+2][col] | ((unsigned)pk[jb+3][col] << 16);
      o.z = (unsigned)pk[jb+4][col] | ((unsigned)pk[jb+5][col] << 16);
      o.w = (unsigned)pk[jb+6][col] | ((unsigned)pk[jb+7][col] << 16);
      frag[((size_t)kb*NTILES + n)*64 + l] = o;
    }
  }
}

// ---------------------------------------------------------------- k_main
// accum[ks][8192][132] = adj[:, ks-slice] @ B[ks-slice, 144]  (bf16 MFMA, fp32 acc)
// 4-strip waves: 2 waves/block x 64 rows/wave (4 x 16-row MFMA strips) — one
// 9 KB B-load per wave per kk feeds 36 MFMAs; per-group s_barrier keeps the
// 2 waves lockstep so the second wave's B-loads hit L1. Bitmask A (ballot
// layout): per 8-kk group a strip's bits are 32 B (2 x i32x4), next group
// prefetched in named regs. B register-double-buffered. No LDS. ~330 VGPR at
// launch_bounds(128,1); grid 512 = 2 blocks/CU.  [unchanged from round 8]
__global__ __launch_bounds__(128, 1) void k_main(const unsigned long long* __restrict__ bm64,
                                                 const uint4* __restrict__ fragB,
                                                 float* __restrict__ accum) {
  const int mb = blockIdx.x >> 3;         // 0..63
  const int ks = blockIdx.x & 7;          // 0..7
  const int tid = threadIdx.x;
  const int wave = tid >> 6, lane = tid & 63;
  const int m16 = lane & 15, quad = lane >> 4;
  const int q2 = quad * 2;

  const int row0 = mb*128 + wave*64 + m16;              // strip0 row
  const char* abase = (const char*)bm64 + (size_t)row0*1024 + ks*128;
  const uu32x4* bb = (const uu32x4*)fragB + (size_t)(ks*32)*NTILES*64 + lane;

  f32x4 acc[4][NTILES];
#pragma unroll
  for (int s = 0; s < 4; s++)
#pragma unroll
    for (int n = 0; n < NTILES; n++) acc[s][n] = (f32x4){0.f, 0.f, 0.f, 0.f};

  uu32x4 bvA[NTILES], bvB[NTILES];
  i32x4 cA[4], cB[4];                     // current A group per strip
  i32x4 nA[4], nB[4];                     // next A group

  auto unpack = [&](unsigned w0, unsigned w1, unsigned w2, unsigned w3,
                    int s) -> bf16x8 {
    const unsigned t0 = (w0 >> s) & 3u;
    const unsigned t1 = (w1 >> s) & 3u;
    const unsigned t2 = (w2 >> s) & 3u;
    const unsigned t3 = (w3 >> s) & 3u;
    unsigned u0 = (t0 & 1u ? 0x3F80u : 0u) | (t1 & 1u ? 0x3F800000u : 0u);
    unsigned u1 = (t2 & 1u ? 0x3F80u : 0u) | (t3 & 1u ? 0x3F800000u : 0u);
    unsigned u2 = (t0 & 2u ? 0x3F80u : 0u) | (t1 & 2u ? 0x3F800000u : 0u);
    unsigned u3 = (t2 & 2u ? 0x3F80u : 0u) | (t3 & 2u ? 0x3F800000u : 0u);
    uu32x4 u = {u0, u1, u2, u3};
    return __builtin_bit_cast(bf16x8, u);
  };

  // prologue: A group 0 (all strips), B(0)
#pragma unroll
  for (int s = 0; s < 4; s++) {
    const i32x4* p = (const i32x4*)(abase + s*16384);
    cA[s] = p[0]; cB[s] = p[1];
  }
#pragma unroll
  for (int t = 0; t < NTILES; t++) bvA[t] = bb[(size_t)t*64];

  for (int g = 0; g < 4; ++g) {           // 4 groups x 8 kk-steps
    __builtin_amdgcn_s_barrier();         // loose 2-wave sync -> L1 B-reuse
    // prefetch next A group (g=3 over-reads 32 B into ws past bm64 — unused)
#pragma unroll
    for (int s = 0; s < 4; s++) {
      const i32x4* p = (const i32x4*)(abase + s*16384 + (g + 1)*32);
      nA[s] = p[0]; nB[s] = p[1];
    }
#pragma unroll
    for (int j = 0; j < 8; ++j) {
      const int kk = g*8 + j;
      // load B(kk+1) into the buffer not in use (kk=31 over-reads 9 KB into ws — safe)
      const uu32x4* bp = bb + (size_t)(kk + 1)*NTILES*64;
      if ((j & 1) == 0) {
#pragma unroll
        for (int t = 0; t < NTILES; t++) bvB[t] = bp[(size_t)t*64];
      } else {
#pragma unroll
        for (int t = 0; t < NTILES; t++) bvA[t] = bp[(size_t)t*64];
      }
      const int sh = (j & 3)*8 + q2;      // static after unroll
      bf16x8 af[4];
#pragma unroll
      for (int s = 0; s < 4; s++) {
        if (j < 4)
          af[s] = unpack((unsigned)cA[s][0], (unsigned)cA[s][2],
                         (unsigned)cB[s][0], (unsigned)cB[s][2], sh);
        else
          af[s] = unpack((unsigned)cA[s][1], (unsigned)cA[s][3],
                         (unsigned)cB[s][1], (unsigned)cB[s][3], sh);
      }
      const uu32x4* bv = ((j & 1) == 0) ? bvA : bvB;   // static after unroll
#pragma unroll
      for (int s = 0; s < 4; s++)
#pragma unroll
        for (int n = 0; n < NTILES; n++) {
          bf16x8 bfr = __builtin_bit_cast(bf16x8, bv[n]);
          acc[s][n] = __builtin_amdgcn_mfma_f32_16x16x32_bf16(af[s], bfr, acc[s][n], 0, 0, 0);
        }
    }
#pragma unroll
    for (int s = 0; s < 4; s++) { cA[s] = nA[s]; cB[s] = nB[s]; }
  }

  // epilogue: C/D layout col=lane&15, row=quad*4+reg. Plain stores.
  float* op = accum + (size_t)ks*N_NODES*ACC_STRIDE;
#pragma unroll
  for (int s = 0; s < 4; s++) {
    const int rb = mb*128 + wave*64 + s*16 + quad*4;
#pragma unroll
    for (int n = 0; n < NTILES; n++) {
      if (n == 8 && m16 >= HEADS) continue;  // cols 130..143 are padding
#pragma unroll
      for (int r = 0; r < 4; r++)
        op[(size_t)(rb + r)*ACC_STRIDE + n*16 + m16] = acc[s][n][r];
    }
  }
}

// ---------------------------------------------------------------- k_div
// out[i][c] = (sum_ks num) / (sum_ks den); vectorized f32x4, 8 rows/block.
__global__ void k_div(const float* __restrict__ acc, float* __restrict__ out) {
  const int tid = threadIdx.x;
  const int r = tid >> 5, c4 = (tid & 31) << 2;   // 8 rows x 32 lanes x float4
  const int i = blockIdx.x * 8 + r;
  const int h = c4 >> 6;
  f32x4 num = (f32x4){0.f, 0.f, 0.f, 0.f};
  float den = 0.f;
#pragma unroll
  for (int s = 0; s < KSPLIT; s++) {
    const float* p = acc + ((size_t)s*N_NODES + i)*ACC_STRIDE;
    num += *(const f32x4*)(p + c4);
    den += p[FEAT + h];
  }
  f32x4 o = num / (f32x4){den, den, den, den};
  *(f32x4*)(out + (size_t)i*FEAT + c4) = o;
}

// ---------------------------------------------------------------- launch
extern "C" void kernel_launch(void* const* d_in, const int* in_sizes, int n_in,
                              void* d_out, int out_size, void* d_ws, size_t ws_size,
                              hipStream_t stream) {
  const float* x      = (const float*)d_in[0];
  const int*   adj    = (const int*)  d_in[1];
  const float* W      = (const float*)d_in[2];
  // d_in[3] = attn_l: cancels in softmax over j — unused.
  const float* attn_r = (const float*)d_in[4];

  char* ws = (char*)d_ws;
  uint4*              frag = (uint4*)(ws + 0);                 // 2.36 MB
  unsigned long long* bm64 = (unsigned long long*)(ws + (4u << 20));  // 8 MB @ 4 MB
  float*              acc  = (float*)(ws + (16u << 20));       // 8 x 4.33 MB @ 16 MB
  float*              out  = (float*)d_out;

  hipLaunchKernelGGL(k_prep_pack, dim3(PREP_BLOCKS + 2048), dim3(256), 0, stream,
                     x, W, attn_r, adj, frag, bm64);
  hipLaunchKernelGGL(k_main, dim3(512),  dim3(128), 0, stream, bm64, frag, acc);
  hipLaunchKernelGGL(k_div,  dim3(1024), dim3(256), 0, stream, acc, out);
}

// Round 10
// 407.836 us; speedup vs baseline: 1.0326x; 1.0326x over previous
//
#include <hip/hip_runtime.h>
#include <cstdint>
#include <cstddef>

#define N_NODES 8192
#define IN_DIM  256
#define OUT_DIM 64
#define HEADS   2
#define FEAT    128           // OUT_DIM*HEADS
#define NTILES  9             // 144 B-cols: 128 feat + 2 denom + 14 pad
#define ACC_STRIDE 132
#define KSPLIT  8

typedef __bf16 bf16x8 __attribute__((ext_vector_type(8)));
typedef float  f32x4  __attribute__((ext_vector_type(4)));
typedef int    i32x4  __attribute__((ext_vector_type(4)));
typedef unsigned uu32x4 __attribute__((ext_vector_type(4)));

static __device__ __forceinline__ unsigned short f2bf(float f) {
  unsigned u = __float_as_uint(f);
  u += 0x7FFFu + ((u >> 16) & 1u);     // round-to-nearest-even
  return (unsigned short)(u >> 16);
}

// ---------------------------------------------------------------- k_pack
// Streaming bit-pack: 268 MB adj -> 8 MB bitmask. Wave reads 1 KB contiguous
// per instruction; ballot transpose; chunk c (cols c*256..+255) -> 4 u64 m_j,
// bit w of m_j = adj[row][c*256 + w*4 + j]. Layout bm64[row*128 + c*4 + j].
// NOTE: keep standalone — fusing with prep regressed twice (r5: strided reads,
// r9: −11 µs even coalesced under prep's 53 KB LDS / 184 VGPR). Mechanism of
// the fused slowdown not understood; do not re-fuse without counter evidence.
__global__ __launch_bounds__(256) void k_pack(const int* __restrict__ adj,
                                              unsigned long long* __restrict__ bm64) {
  const int tid = threadIdx.x;
  const int wv = tid >> 6, lane = tid & 63;
  const int row = blockIdx.x * 4 + wv;
  const i32x4* rp = (const i32x4*)(adj + (size_t)row * N_NODES) + lane;
  unsigned long long* op = bm64 + (size_t)row * 128;

  for (int c = 0; c < 32; c += 8) {
    i32x4 v[8];
#pragma unroll
    for (int i = 0; i < 8; ++i)
      v[i] = __builtin_nontemporal_load(rp + (size_t)(c + i) * 64);
#pragma unroll
    for (int i = 0; i < 8; ++i) {
      unsigned long long m0 = __ballot(v[i][0] != 0);
      unsigned long long m1 = __ballot(v[i][1] != 0);
      unsigned long long m2 = __ballot(v[i][2] != 0);
      unsigned long long m3 = __ballot(v[i][3] != 0);
      unsigned long long mv = (lane == 0) ? m0 : (lane == 1) ? m1
                            : (lane == 2) ? m2 : m3;
      if (lane < 4) op[(c + i) * 4 + lane] = mv;
    }
  }
}

// ---------------------------------------------------------------- k_prep
// Fused: H-tile matmul (registers) + er reduction + exp + bf16 fragment pack.
__global__ __launch_bounds__(256) void k_prep(const float* __restrict__ x,
                                              const float* __restrict__ W,
                                              const float* __restrict__ attn_r,
                                              uint4* __restrict__ frag) {
  const int kb = blockIdx.x;                 // 0..255
  const int tid = threadIdx.x;
  const int tx = tid & 15, ty = tid >> 4;    // ty 0..15
  const int j0 = kb * 32;

  __shared__ float xs[32][68];               // [row][k] 8.7 KB
  __shared__ float wl[128][68];              // [col][k] 34.8 KB
  __shared__ unsigned short pk[32][146];     // bf16 pack buffer 9.3 KB

  float acc[2][8] = {};                      // rows ty, ty+16; cols tx+jj*16

  for (int kc = 0; kc < IN_DIM; kc += 64) {
    __syncthreads();
#pragma unroll
    for (int p = 0; p < 2; p++) {
      const int slot = p*256 + tid;
      const int r = slot >> 4, k4 = slot & 15;
      *(float4*)&xs[r][k4*4] = *(const float4*)(x + (size_t)(j0 + r)*IN_DIM + kc + k4*4);
    }
#pragma unroll
    for (int p = 0; p < 8; p++) {
      const int slot = p*256 + tid;
      const int r = slot >> 4, k4 = slot & 15;
      *(float4*)&wl[r][k4*4] = *(const float4*)(W + (size_t)r*IN_DIM + kc + k4*4);
    }
    __syncthreads();
#pragma unroll
    for (int k4 = 0; k4 < 16; k4++) {
      float4 xr[2], wr[8];
#pragma unroll
      for (int i = 0; i < 2; i++) xr[i] = *(const float4*)&xs[ty + i*16][k4*4];
#pragma unroll
      for (int jj = 0; jj < 8; jj++) wr[jj] = *(const float4*)&wl[tx + jj*16][k4*4];
#pragma unroll
      for (int i = 0; i < 2; i++)
#pragma unroll
        for (int jj = 0; jj < 8; jj++)
          acc[i][jj] += xr[i].x*wr[jj].x + xr[i].y*wr[jj].y +
                        xr[i].z*wr[jj].z + xr[i].w*wr[jj].w;
    }
  }

  float ar[8];
#pragma unroll
  for (int jj = 0; jj < 8; jj++)
    ar[jj] = attn_r[((jj >> 2)) * OUT_DIM + ((tx + jj*16) & 63)];
  float e0[2] = {}, e1[2] = {};
#pragma unroll
  for (int i = 0; i < 2; i++) {
#pragma unroll
    for (int jj = 0; jj < 4; jj++) e0[i] += acc[i][jj] * ar[jj];
#pragma unroll
    for (int jj = 4; jj < 8; jj++) e1[i] += acc[i][jj] * ar[jj];
  }
#pragma unroll
  for (int m = 1; m <= 8; m <<= 1) {
#pragma unroll
    for (int i = 0; i < 2; i++) {
      e0[i] += __shfl_xor(e0[i], m);
      e1[i] += __shfl_xor(e1[i], m);
    }
  }
  float w0[2], w1[2];
#pragma unroll
  for (int i = 0; i < 2; i++) { w0[i] = __expf(e0[i]); w1[i] = __expf(e1[i]); }

#pragma unroll
  for (int i = 0; i < 2; i++) {
    const int row = ty + i*16;
#pragma unroll
    for (int jj = 0; jj < 8; jj++)
      pk[row][tx + jj*16] = f2bf((jj < 4 ? w0[i] : w1[i]) * acc[i][jj]);
    pk[row][128 + tx] = (tx == 0) ? f2bf(w0[i]) : (tx == 1) ? f2bf(w1[i]) : 0;
  }
  __syncthreads();

#pragma unroll
  for (int t = 0; t < 3; t++) {
    const int wid = t*256 + tid;
    if (wid < 576) {
      const int l = wid & 63, n = wid >> 6;
      const int col = n*16 + (l & 15), jb = (l >> 4) * 8;
      uint4 o;
      o.x = (unsigned)pk[jb+0][col] | ((unsigned)pk[jb+1][col] << 16);
      o.y = (unsigned)pk[jb+2][col] | ((unsigned)pk[jb+3][col] << 16);
      o.z = (unsigned)pk[jb+4][col] | ((unsigned)pk[jb+5][col] << 16);
      o.w = (unsigned)pk[jb+6][col] | ((unsigned)pk[jb+7][col] << 16);
      frag[((size_t)kb*NTILES + n)*64 + l] = o;
    }
  }
}

// ---------------------------------------------------------------- k_main
// accum[ks][8192][132] = adj[:, ks-slice] @ B[ks-slice, 144]  (bf16 MFMA, fp32 acc)
// 4-strip waves: 2 waves/block x 64 rows/wave (4 x 16-row MFMA strips) — one
// 9 KB B-load per wave per kk feeds 36 MFMAs; per-group s_barrier keeps the
// 2 waves lockstep so the second wave's B-loads hit L1. ks = blockIdx&7 puts
// co-resident blocks (b, b+256) on the same ks -> shared B panel, and each
// XCD's L2 holds only its own 295 KB B slice. Bitmask A (ballot layout): per
// 8-kk group a strip's bits are 32 B (2 x i32x4), next group prefetched in
// named regs. B register-double-buffered. No LDS. ~330 VGPR at
// launch_bounds(128,1); grid 512 = 2 blocks/CU = 4 waves/CU (4 SIMDs busy).
__global__ __launch_bounds__(128, 1) void k_main(const unsigned long long* __restrict__ bm64,
                                                 const uint4* __restrict__ fragB,
                                                 float* __restrict__ accum) {
  const int mb = blockIdx.x >> 3;         // 0..63
  const int ks = blockIdx.x & 7;          // 0..7
  const int tid = threadIdx.x;
  const int wave = tid >> 6, lane = tid & 63;
  const int m16 = lane & 15, quad = lane >> 4;
  const int q2 = quad * 2;

  const int row0 = mb*128 + wave*64 + m16;              // strip0 row
  const char* abase = (const char*)bm64 + (size_t)row0*1024 + ks*128;
  const uu32x4* bb = (const uu32x4*)fragB + (size_t)(ks*32)*NTILES*64 + lane;

  f32x4 acc[4][NTILES];
#pragma unroll
  for (int s = 0; s < 4; s++)
#pragma unroll
    for (int n = 0; n < NTILES; n++) acc[s][n] = (f32x4){0.f, 0.f, 0.f, 0.f};

  uu32x4 bvA[NTILES], bvB[NTILES];
  i32x4 cA[4], cB[4];                     // current A group per strip
  i32x4 nA[4], nB[4];                     // next A group

  auto unpack = [&](unsigned w0, unsigned w1, unsigned w2, unsigned w3,
                    int s) -> bf16x8 {
    const unsigned t0 = (w0 >> s) & 3u;
    const unsigned t1 = (w1 >> s) & 3u;
    const unsigned t2 = (w2 >> s) & 3u;
    const unsigned t3 = (w3 >> s) & 3u;
    unsigned u0 = (t0 & 1u ? 0x3F80u : 0u) | (t1 & 1u ? 0x3F800000u : 0u);
    unsigned u1 = (t2 & 1u ? 0x3F80u : 0u) | (t3 & 1u ? 0x3F800000u : 0u);
    unsigned u2 = (t0 & 2u ? 0x3F80u : 0u) | (t1 & 2u ? 0x3F800000u : 0u);
    unsigned u3 = (t2 & 2u ? 0x3F80u : 0u) | (t3 & 2u ? 0x3F800000u : 0u);
    uu32x4 u = {u0, u1, u2, u3};
    return __builtin_bit_cast(bf16x8, u);
  };

  // prologue: A group 0 (all strips), B(0)
#pragma unroll
  for (int s = 0; s < 4; s++) {
    const i32x4* p = (const i32x4*)(abase + s*16384);
    cA[s] = p[0]; cB[s] = p[1];
  }
#pragma unroll
  for (int t = 0; t < NTILES; t++) bvA[t] = bb[(size_t)t*64];

  for (int g = 0; g < 4; ++g) {           // 4 groups x 8 kk-steps
    __builtin_amdgcn_s_barrier();         // loose 2-wave sync -> L1 B-reuse
    // prefetch next A group (g=3 over-reads 32 B into ws past bm64 — unused)
#pragma unroll
    for (int s = 0; s < 4; s++) {
      const i32x4* p = (const i32x4*)(abase + s*16384 + (g + 1)*32);
      nA[s] = p[0]; nB[s] = p[1];
    }
#pragma unroll
    for (int j = 0; j < 8; ++j) {
      const int kk = g*8 + j;
      // load B(kk+1) into the buffer not in use (kk=31 over-reads 9 KB into ws — safe)
      const uu32x4* bp = bb + (size_t)(kk + 1)*NTILES*64;
      if ((j & 1) == 0) {
#pragma unroll
        for (int t = 0; t < NTILES; t++) bvB[t] = bp[(size_t)t*64];
      } else {
#pragma unroll
        for (int t = 0; t < NTILES; t++) bvA[t] = bp[(size_t)t*64];
      }
      const int sh = (j & 3)*8 + q2;      // static after unroll
      bf16x8 af[4];
#pragma unroll
      for (int s = 0; s < 4; s++) {
        if (j < 4)
          af[s] = unpack((unsigned)cA[s][0], (unsigned)cA[s][2],
                         (unsigned)cB[s][0], (unsigned)cB[s][2], sh);
        else
          af[s] = unpack((unsigned)cA[s][1], (unsigned)cA[s][3],
                         (unsigned)cB[s][1], (unsigned)cB[s][3], sh);
      }
      const uu32x4* bv = ((j & 1) == 0) ? bvA : bvB;   // static after unroll
#pragma unroll
      for (int s = 0; s < 4; s++)
#pragma unroll
        for (int n = 0; n < NTILES; n++) {
          bf16x8 bfr = __builtin_bit_cast(bf16x8, bv[n]);
          acc[s][n] = __builtin_amdgcn_mfma_f32_16x16x32_bf16(af[s], bfr, acc[s][n], 0, 0, 0);
        }
    }
#pragma unroll
    for (int s = 0; s < 4; s++) { cA[s] = nA[s]; cB[s] = nB[s]; }
  }

  // epilogue: C/D layout col=lane&15, row=quad*4+reg. Plain stores.
  float* op = accum + (size_t)ks*N_NODES*ACC_STRIDE;
#pragma unroll
  for (int s = 0; s < 4; s++) {
    const int rb = mb*128 + wave*64 + s*16 + quad*4;
#pragma unroll
    for (int n = 0; n < NTILES; n++) {
      if (n == 8 && m16 >= HEADS) continue;  // cols 130..143 are padding
#pragma unroll
      for (int r = 0; r < 4; r++)
        op[(size_t)(rb + r)*ACC_STRIDE + n*16 + m16] = acc[s][n][r];
    }
  }
}

// ---------------------------------------------------------------- k_div
// out[i][c] = (sum_ks num) / (sum_ks den); vectorized f32x4, 8 rows/block.
__global__ void k_div(const float* __restrict__ acc, float* __restrict__ out) {
  const int tid = threadIdx.x;
  const int r = tid >> 5, c4 = (tid & 31) << 2;   // 8 rows x 32 lanes x float4
  const int i = blockIdx.x * 8 + r;
  const int h = c4 >> 6;
  f32x4 num = (f32x4){0.f, 0.f, 0.f, 0.f};
  float den = 0.f;
#pragma unroll
  for (int s = 0; s < KSPLIT; s++) {
    const float* p = acc + ((size_t)s*N_NODES + i)*ACC_STRIDE;
    num += *(const f32x4*)(p + c4);
    den += p[FEAT + h];
  }
  f32x4 o = num / (f32x4){den, den, den, den};
  *(f32x4*)(out + (size_t)i*FEAT + c4) = o;
}

// ---------------------------------------------------------------- launch
extern "C" void kernel_launch(void* const* d_in, const int* in_sizes, int n_in,
                              void* d_out, int out_size, void* d_ws, size_t ws_size,
                              hipStream_t stream) {
  const float* x      = (const float*)d_in[0];
  const int*   adj    = (const int*)  d_in[1];
  const float* W      = (const float*)d_in[2];
  // d_in[3] = attn_l: cancels in softmax over j — unused.
  const float* attn_r = (const float*)d_in[4];

  char* ws = (char*)d_ws;
  uint4*              frag = (uint4*)(ws + 0);                 // 2.36 MB
  unsigned long long* bm64 = (unsigned long long*)(ws + (4u << 20));  // 8 MB @ 4 MB
  float*              acc  = (float*)(ws + (16u << 20));       // 8 x 4.33 MB @ 16 MB
  float*              out  = (float*)d_out;

  hipLaunchKernelGGL(k_pack, dim3(2048), dim3(256), 0, stream, adj, bm64);
  hipLaunchKernelGGL(k_prep, dim3(256),  dim3(256), 0, stream, x, W, attn_r, frag);
  hipLaunchKernelGGL(k_main, dim3(512),  dim3(128), 0, stream, bm64, frag, acc);
  hipLaunchKernelGGL(k_div,  dim3(1024), dim3(256), 0, stream, acc, out);
}